// Round 1
// baseline (830.038 us; speedup 1.0000x reference)
//
#include <hip/hip_runtime.h>

static constexpr int N = 100000;
static constexpr int E = 3200000;

// ws layout (floats): deg[N] dinv[N] acc1[N] s1[N] tpos[N] tneg[N] sum16[16]

__global__ void k_init(float* __restrict__ deg, float* __restrict__ acc1,
                       float* __restrict__ tpos, float* __restrict__ tneg,
                       float* __restrict__ sum16) {
    int i = blockIdx.x * blockDim.x + threadIdx.x;
    if (i < N) { deg[i] = 1.0f; acc1[i] = 0.f; tpos[i] = 0.f; tneg[i] = 0.f; }
    if (i < 16) sum16[i] = 0.f;
}

// deg[v] = 1 (self-loop) + in-degree(v)
__global__ void k_deg(const int* __restrict__ col, float* __restrict__ deg) {
    int e = blockIdx.x * blockDim.x + threadIdx.x;
    if (e < E) atomicAdd(&deg[col[e]], 1.0f);
}

__global__ void k_dinv(const float* __restrict__ deg, float* __restrict__ dinv) {
    int i = blockIdx.x * blockDim.x + threadIdx.x;
    if (i < N) dinv[i] = 1.0f / sqrtf(deg[i]);
}

// acc1[c] += dinv[r] * x[r]
__global__ void k_edge1(const int* __restrict__ ei, const float* __restrict__ x,
                        const float* __restrict__ dinv, float* __restrict__ acc1) {
    int e = blockIdx.x * blockDim.x + threadIdx.x;
    if (e < E) {
        int r = ei[e], c = ei[E + e];
        atomicAdd(&acc1[c], dinv[r] * x[r]);
    }
}

// s1[v] = dinv[v]*(acc1[v] + dinv[v]*x[v])  -- layer-1 aggregated scalar
__global__ void k_s1(const float* __restrict__ dinv, const float* __restrict__ acc1,
                     const float* __restrict__ x, float* __restrict__ s1) {
    int i = blockIdx.x * blockDim.x + threadIdx.x;
    if (i < N) { float d = dinv[i]; s1[i] = d * (acc1[i] + d * x[i]); }
}

// sign-split scalar aggregation for layer 2
__global__ void k_edge2(const int* __restrict__ ei, const float* __restrict__ dinv,
                        const float* __restrict__ s1, float* __restrict__ tpos,
                        float* __restrict__ tneg) {
    int e = blockIdx.x * blockDim.x + threadIdx.x;
    if (e < E) {
        int r = ei[e], c = ei[E + e];
        float s = s1[r];
        float m = dinv[r] * s;
        if (s >= 0.f) atomicAdd(&tpos[c], m);
        else          atomicAdd(&tneg[c], m);
    }
}

// h2[v][j] = relu(alpha[v]*P[j] + beta[v]*M[j]); accumulate column sums
__global__ void k_nodes(const float* __restrict__ dinv, const float* __restrict__ s1,
                        const float* __restrict__ tpos, const float* __restrict__ tneg,
                        const float* __restrict__ W1, const float* __restrict__ W2,
                        float* __restrict__ sum16) {
    __shared__ float sP[16], sM[16];
    if (threadIdx.x < 16) {
        float p = 0.f, m = 0.f;
        for (int k = 0; k < 16; ++k) {
            float w1 = W1[k];
            float w2 = W2[k * 16 + threadIdx.x];
            p += fmaxf(w1, 0.f) * w2;
            m += fminf(w1, 0.f) * w2;
        }
        sP[threadIdx.x] = p; sM[threadIdx.x] = m;
    }
    __syncthreads();

    int v = blockIdx.x * blockDim.x + threadIdx.x;
    float alpha = 0.f, beta = 0.f;
    if (v < N) {
        float d = dinv[v], s = s1[v];
        alpha = d * tpos[v];
        beta  = d * tneg[v];
        float self = d * d * s;
        if (s >= 0.f) alpha += self; else beta += self;
    }
    int lane = threadIdx.x & 63;
    for (int j = 0; j < 16; ++j) {
        float h = fmaxf(alpha * sP[j] + beta * sM[j], 0.f);
        #pragma unroll
        for (int off = 32; off > 0; off >>= 1) h += __shfl_down(h, off);
        if (lane == 0) atomicAdd(&sum16[j], h);
    }
}

// out[o] = b[o] + sum_j (sum16[j]/N) * W3[j][o]
__global__ void k_out(const float* __restrict__ sum16, const float* __restrict__ W3,
                      const float* __restrict__ b, float* __restrict__ out) {
    int o = threadIdx.x;
    if (o < 11) {
        float acc = b[o];
        const float invn = 1.0f / (float)N;
        for (int j = 0; j < 16; ++j) acc += (sum16[j] * invn) * W3[j * 11 + o];
        out[o] = acc;
    }
}

extern "C" void kernel_launch(void* const* d_in, const int* in_sizes, int n_in,
                              void* d_out, int out_size, void* d_ws, size_t ws_size,
                              hipStream_t stream) {
    const float* x  = (const float*)d_in[0];
    const int*   ei = (const int*)d_in[1];   // edge_index as int32, [2*E] flat
    const float* W1 = (const float*)d_in[2];
    const float* W2 = (const float*)d_in[3];
    const float* W3 = (const float*)d_in[4];
    const float* b  = (const float*)d_in[5];
    float* out = (float*)d_out;

    float* ws    = (float*)d_ws;
    float* deg   = ws;
    float* dinv  = ws + (size_t)N;
    float* acc1  = ws + (size_t)2 * N;
    float* s1    = ws + (size_t)3 * N;
    float* tpos  = ws + (size_t)4 * N;
    float* tneg  = ws + (size_t)5 * N;
    float* sum16 = ws + (size_t)6 * N;

    const int nb_n = (N + 255) / 256;
    const int nb_e = (E + 255) / 256;

    k_init <<<nb_n, 256, 0, stream>>>(deg, acc1, tpos, tneg, sum16);
    k_deg  <<<nb_e, 256, 0, stream>>>(ei + E, deg);
    k_dinv <<<nb_n, 256, 0, stream>>>(deg, dinv);
    k_edge1<<<nb_e, 256, 0, stream>>>(ei, x, dinv, acc1);
    k_s1   <<<nb_n, 256, 0, stream>>>(dinv, acc1, x, s1);
    k_edge2<<<nb_e, 256, 0, stream>>>(ei, dinv, s1, tpos, tneg);
    k_nodes<<<nb_n, 256, 0, stream>>>(dinv, s1, tpos, tneg, W1, W2, sum16);
    k_out  <<<1, 64, 0, stream>>>(sum16, W3, b, out);
}

// Round 2
// 518.806 us; speedup vs baseline: 1.5999x; 1.5999x over previous
//
#include <hip/hip_runtime.h>

static constexpr int N = 100000;
static constexpr int E = 3200000;
static constexpr int NB_N = (N + 255) / 256;   // 391 node blocks

// ws layout (floats):
//   deg[N] dinv[N] y1[N] acc1[N] m[N] tpos[N] tneg[N] partials[NB_N*16]

__global__ void k_init(float* __restrict__ deg, float* __restrict__ acc1,
                       float* __restrict__ tpos, float* __restrict__ tneg) {
    int i = blockIdx.x * blockDim.x + threadIdx.x;
    if (i < N) { deg[i] = 1.0f; acc1[i] = 0.f; tpos[i] = 0.f; tneg[i] = 0.f; }
}

// deg[v] = 1 (self-loop) + in-degree(v); 4 edges/thread
__global__ void k_deg(const int4* __restrict__ col4, float* __restrict__ deg) {
    int t = blockIdx.x * blockDim.x + threadIdx.x;
    if (t < E / 4) {
        int4 c = col4[t];
        atomicAdd(&deg[c.x], 1.0f);
        atomicAdd(&deg[c.y], 1.0f);
        atomicAdd(&deg[c.z], 1.0f);
        atomicAdd(&deg[c.w], 1.0f);
    }
}

// dinv = rsqrt(deg); y1 = dinv * x
__global__ void k_dinv(const float* __restrict__ deg, const float* __restrict__ x,
                       float* __restrict__ dinv, float* __restrict__ y1) {
    int i = blockIdx.x * blockDim.x + threadIdx.x;
    if (i < N) {
        float d = rsqrtf(deg[i]);
        dinv[i] = d;
        y1[i] = d * x[i];
    }
}

// acc1[c] += y1[r]; 4 edges/thread, single gather per edge
__global__ void k_edge1(const int4* __restrict__ row4, const int4* __restrict__ col4,
                        const float* __restrict__ y1, float* __restrict__ acc1) {
    int t = blockIdx.x * blockDim.x + threadIdx.x;
    if (t < E / 4) {
        int4 r = row4[t];
        int4 c = col4[t];
        atomicAdd(&acc1[c.x], y1[r.x]);
        atomicAdd(&acc1[c.y], y1[r.y]);
        atomicAdd(&acc1[c.z], y1[r.z]);
        atomicAdd(&acc1[c.w], y1[r.w]);
    }
}

// m[v] = dinv[v] * s1[v],  s1 = dinv*(acc1 + dinv*x)
__global__ void k_s1(const float* __restrict__ dinv, const float* __restrict__ acc1,
                     const float* __restrict__ x, float* __restrict__ m) {
    int i = blockIdx.x * blockDim.x + threadIdx.x;
    if (i < N) {
        float d = dinv[i];
        float s = d * (acc1[i] + d * x[i]);
        m[i] = d * s;
    }
}

// sign-split scalar aggregation for layer 2; single gather per edge
__global__ void k_edge2(const int4* __restrict__ row4, const int4* __restrict__ col4,
                        const float* __restrict__ m, float* __restrict__ tpos,
                        float* __restrict__ tneg) {
    int t = blockIdx.x * blockDim.x + threadIdx.x;
    if (t < E / 4) {
        int4 r = row4[t];
        int4 c = col4[t];
        float v0 = m[r.x], v1 = m[r.y], v2 = m[r.z], v3 = m[r.w];
        atomicAdd(v0 >= 0.f ? &tpos[c.x] : &tneg[c.x], v0);
        atomicAdd(v1 >= 0.f ? &tpos[c.y] : &tneg[c.y], v1);
        atomicAdd(v2 >= 0.f ? &tpos[c.z] : &tneg[c.z], v2);
        atomicAdd(v3 >= 0.f ? &tpos[c.w] : &tneg[c.w], v3);
    }
}

// h2[v][j] = relu(alpha*P[j] + beta*M[j]); per-block partial column sums (no global atomics)
__global__ void k_nodes(const float* __restrict__ dinv, const float* __restrict__ m,
                        const float* __restrict__ tpos, const float* __restrict__ tneg,
                        const float* __restrict__ W1, const float* __restrict__ W2,
                        float* __restrict__ partials) {
    __shared__ float sP[16], sM[16], sAcc[16];
    if (threadIdx.x < 16) {
        float p = 0.f, q = 0.f;
        for (int k = 0; k < 16; ++k) {
            float w1 = W1[k];
            float w2 = W2[k * 16 + threadIdx.x];
            p += fmaxf(w1, 0.f) * w2;
            q += fminf(w1, 0.f) * w2;
        }
        sP[threadIdx.x] = p; sM[threadIdx.x] = q;
        sAcc[threadIdx.x] = 0.f;
    }
    __syncthreads();

    int v = blockIdx.x * blockDim.x + threadIdx.x;
    float alpha = 0.f, beta = 0.f;
    if (v < N) {
        float d = dinv[v], mv = m[v];
        alpha = d * tpos[v];
        beta  = d * tneg[v];
        float self = d * mv;            // = dinv^2 * s1
        if (mv >= 0.f) alpha += self; else beta += self;
    }
    int lane = threadIdx.x & 63;
    for (int j = 0; j < 16; ++j) {
        float h = fmaxf(alpha * sP[j] + beta * sM[j], 0.f);
        #pragma unroll
        for (int off = 32; off > 0; off >>= 1) h += __shfl_down(h, off);
        if (lane == 0) atomicAdd(&sAcc[j], h);   // LDS atomic, 4 waves
    }
    __syncthreads();
    if (threadIdx.x < 16) partials[blockIdx.x * 16 + threadIdx.x] = sAcc[threadIdx.x];
}

// reduce partials[NB_N][16] -> mean -> out = g @ W3 + b
__global__ void k_out(const float* __restrict__ partials, const float* __restrict__ W3,
                      const float* __restrict__ b, float* __restrict__ out) {
    __shared__ float s[16][16];   // [group][j]
    int j = threadIdx.x & 15;
    int g = threadIdx.x >> 4;     // 16 groups
    float acc = 0.f;
    for (int blk = g; blk < NB_N; blk += 16) acc += partials[blk * 16 + j];
    s[g][j] = acc;
    __syncthreads();
    if (threadIdx.x < 16) {
        float tot = 0.f;
        #pragma unroll
        for (int gg = 0; gg < 16; ++gg) tot += s[gg][threadIdx.x];
        s[0][threadIdx.x] = tot * (1.0f / (float)N);   // mean over nodes
    }
    __syncthreads();
    if (threadIdx.x < 11) {
        float acc2 = b[threadIdx.x];
        #pragma unroll
        for (int k = 0; k < 16; ++k) acc2 += s[0][k] * W3[k * 11 + threadIdx.x];
        out[threadIdx.x] = acc2;
    }
}

extern "C" void kernel_launch(void* const* d_in, const int* in_sizes, int n_in,
                              void* d_out, int out_size, void* d_ws, size_t ws_size,
                              hipStream_t stream) {
    const float* x  = (const float*)d_in[0];
    const int*   ei = (const int*)d_in[1];   // [2*E] flat: rows then cols
    const float* W1 = (const float*)d_in[2];
    const float* W2 = (const float*)d_in[3];
    const float* W3 = (const float*)d_in[4];
    const float* b  = (const float*)d_in[5];
    float* out = (float*)d_out;

    float* ws       = (float*)d_ws;
    float* deg      = ws;
    float* dinv     = ws + (size_t)N;
    float* y1       = ws + (size_t)2 * N;
    float* acc1     = ws + (size_t)3 * N;
    float* m        = ws + (size_t)4 * N;
    float* tpos     = ws + (size_t)5 * N;
    float* tneg     = ws + (size_t)6 * N;
    float* partials = ws + (size_t)7 * N;

    const int4* row4 = (const int4*)ei;
    const int4* col4 = (const int4*)(ei + E);

    const int nb_n  = NB_N;
    const int nb_e4 = (E / 4 + 255) / 256;

    k_init <<<nb_n, 256, 0, stream>>>(deg, acc1, tpos, tneg);
    k_deg  <<<nb_e4, 256, 0, stream>>>(col4, deg);
    k_dinv <<<nb_n, 256, 0, stream>>>(deg, x, dinv, y1);
    k_edge1<<<nb_e4, 256, 0, stream>>>(row4, col4, y1, acc1);
    k_s1   <<<nb_n, 256, 0, stream>>>(dinv, acc1, x, m);
    k_edge2<<<nb_e4, 256, 0, stream>>>(row4, col4, m, tpos, tneg);
    k_nodes<<<nb_n, 256, 0, stream>>>(dinv, m, tpos, tneg, W1, W2, partials);
    k_out  <<<1, 256, 0, stream>>>(partials, W3, b, out);
}

// Round 3
// 130.378 us; speedup vs baseline: 6.3664x; 3.9793x over previous
//
#include <hip/hip_runtime.h>

static constexpr int N = 100000;
static constexpr int E = 3200000;          // divisible by 4
static constexpr int BUKSHIFT = 9;
static constexpr int BUKSZ = 1 << BUKSHIFT;            // 512 nodes / bucket
static constexpr int BUKMASK = BUKSZ - 1;
static constexpr int NBUK = (N + BUKSZ - 1) / BUKSZ;   // 196
static constexpr int SC_CHUNK = 8192;                   // edges per scatter block
static constexpr int SC_BLOCKS = (E + SC_CHUNK - 1) / SC_CHUNK;  // 391

// ws layout (4B elems):
//   binned[E] | dinv[N] | y1[N] | m[N] | base[NBUK+1] | gofs[NBUK] | gcount[NBUK] | partials[NBUK*16]

__global__ void k_init(int* __restrict__ gcount) {
    int i = threadIdx.x;
    if (i < NBUK) gcount[i] = 0;
}

// global bucket histogram of cols
__global__ void k_count(const int4* __restrict__ cols4, int* __restrict__ gcount) {
    __shared__ int h[NBUK];
    for (int i = threadIdx.x; i < NBUK; i += blockDim.x) h[i] = 0;
    __syncthreads();
    const int nI4 = E / 4;
    for (int i = blockIdx.x * blockDim.x + threadIdx.x; i < nI4; i += gridDim.x * blockDim.x) {
        int4 c = cols4[i];
        atomicAdd(&h[c.x >> BUKSHIFT], 1);
        atomicAdd(&h[c.y >> BUKSHIFT], 1);
        atomicAdd(&h[c.z >> BUKSHIFT], 1);
        atomicAdd(&h[c.w >> BUKSHIFT], 1);
    }
    __syncthreads();
    for (int i = threadIdx.x; i < NBUK; i += blockDim.x)
        if (h[i]) atomicAdd(&gcount[i], h[i]);
}

// exclusive scan of gcount -> base[0..NBUK], gofs = base
__global__ void k_scan(const int* __restrict__ gcount, int* __restrict__ base,
                       int* __restrict__ gofs) {
    __shared__ int s[256];
    int tid = threadIdx.x;
    int v = (tid < NBUK) ? gcount[tid] : 0;
    s[tid] = v;
    __syncthreads();
    for (int off = 1; off < 256; off <<= 1) {
        int t = (tid >= off) ? s[tid - off] : 0;
        __syncthreads();
        s[tid] += t;
        __syncthreads();
    }
    int excl = s[tid] - v;
    if (tid < NBUK) { base[tid] = excl; gofs[tid] = excl; }
    if (tid == 255) base[NBUK] = s[255];   // == E
}

// scatter edges into bucket-contiguous binned[] as packed (r<<9)|(c&511)
__global__ void k_scatter(const int4* __restrict__ rows4, const int4* __restrict__ cols4,
                          int* __restrict__ gofs, int* __restrict__ binned) {
    __shared__ int h[NBUK];
    __shared__ int bbase[NBUK];
    const int e0 = blockIdx.x * SC_CHUNK;
    const int e1 = min(e0 + SC_CHUNK, E);
    const int i0 = e0 / 4, i1 = e1 / 4;

    for (int i = threadIdx.x; i < NBUK; i += blockDim.x) h[i] = 0;
    __syncthreads();
    for (int i = i0 + threadIdx.x; i < i1; i += blockDim.x) {
        int4 c = cols4[i];
        atomicAdd(&h[c.x >> BUKSHIFT], 1);
        atomicAdd(&h[c.y >> BUKSHIFT], 1);
        atomicAdd(&h[c.z >> BUKSHIFT], 1);
        atomicAdd(&h[c.w >> BUKSHIFT], 1);
    }
    __syncthreads();
    for (int i = threadIdx.x; i < NBUK; i += blockDim.x) {
        int cnt = h[i];
        bbase[i] = cnt ? atomicAdd(&gofs[i], cnt) : 0;
    }
    __syncthreads();
    for (int i = threadIdx.x; i < NBUK; i += blockDim.x) h[i] = 0;
    __syncthreads();
    for (int i = i0 + threadIdx.x; i < i1; i += blockDim.x) {
        int4 r = rows4[i];
        int4 c = cols4[i];
        int b, p;
        b = c.x >> BUKSHIFT; p = bbase[b] + atomicAdd(&h[b], 1); binned[p] = (r.x << BUKSHIFT) | (c.x & BUKMASK);
        b = c.y >> BUKSHIFT; p = bbase[b] + atomicAdd(&h[b], 1); binned[p] = (r.y << BUKSHIFT) | (c.y & BUKMASK);
        b = c.z >> BUKSHIFT; p = bbase[b] + atomicAdd(&h[b], 1); binned[p] = (r.z << BUKSHIFT) | (c.z & BUKMASK);
        b = c.w >> BUKSHIFT; p = bbase[b] + atomicAdd(&h[b], 1); binned[p] = (r.w << BUKSHIFT) | (c.w & BUKMASK);
    }
}

// per-bucket: degree count in LDS -> dinv, y1 (block owns nodes [b*512, b*512+512))
__global__ void k_deg2(const int* __restrict__ binned, const int* __restrict__ base,
                       const float* __restrict__ x, float* __restrict__ dinv,
                       float* __restrict__ y1) {
    __shared__ int cnt[BUKSZ];
    for (int i = threadIdx.x; i < BUKSZ; i += blockDim.x) cnt[i] = 0;
    __syncthreads();
    const int b = blockIdx.x;
    const int s0 = base[b], s1 = base[b + 1];
    for (int i = s0 + threadIdx.x; i < s1; i += blockDim.x)
        atomicAdd(&cnt[binned[i] & BUKMASK], 1);
    __syncthreads();
    const int v0 = b << BUKSHIFT;
    for (int i = threadIdx.x; i < BUKSZ; i += blockDim.x) {
        int v = v0 + i;
        if (v < N) {
            float d = rsqrtf(1.0f + (float)cnt[i]);
            dinv[v] = d;
            y1[v] = d * x[v];
        }
    }
}

// per-bucket: acc1 in LDS -> m = dinv*s1, s1 = dinv*acc + dinv*y1
__global__ void k_acc1(const int* __restrict__ binned, const int* __restrict__ base,
                       const float* __restrict__ y1, const float* __restrict__ dinv,
                       float* __restrict__ m) {
    __shared__ float acc[BUKSZ];
    for (int i = threadIdx.x; i < BUKSZ; i += blockDim.x) acc[i] = 0.f;
    __syncthreads();
    const int b = blockIdx.x;
    const int s0 = base[b], s1 = base[b + 1];
    for (int i = s0 + threadIdx.x; i < s1; i += blockDim.x) {
        int p = binned[i];
        atomicAdd(&acc[p & BUKMASK], y1[p >> BUKSHIFT]);
    }
    __syncthreads();
    const int v0 = b << BUKSHIFT;
    for (int i = threadIdx.x; i < BUKSZ; i += blockDim.x) {
        int v = v0 + i;
        if (v < N) {
            float d = dinv[v];
            float s = d * acc[i] + d * y1[v];
            m[v] = d * s;
        }
    }
}

// per-bucket: tpos/tneg in LDS -> h2 -> per-block partial column sums
__global__ void k_acc2(const int* __restrict__ binned, const int* __restrict__ base,
                       const float* __restrict__ m, const float* __restrict__ dinv,
                       const float* __restrict__ W1, const float* __restrict__ W2,
                       float* __restrict__ partials) {
    __shared__ float tp[BUKSZ], tn[BUKSZ];
    __shared__ float sP[16], sM[16], sAcc[16];
    if (threadIdx.x < 16) {
        float p = 0.f, q = 0.f;
        for (int k = 0; k < 16; ++k) {
            float w1 = W1[k];
            float w2 = W2[k * 16 + threadIdx.x];
            p += fmaxf(w1, 0.f) * w2;
            q += fminf(w1, 0.f) * w2;
        }
        sP[threadIdx.x] = p; sM[threadIdx.x] = q; sAcc[threadIdx.x] = 0.f;
    }
    for (int i = threadIdx.x; i < BUKSZ; i += blockDim.x) { tp[i] = 0.f; tn[i] = 0.f; }
    __syncthreads();
    const int b = blockIdx.x;
    const int s0 = base[b], s1 = base[b + 1];
    for (int i = s0 + threadIdx.x; i < s1; i += blockDim.x) {
        int p = binned[i];
        float val = m[p >> BUKSHIFT];
        atomicAdd(val >= 0.f ? &tp[p & BUKMASK] : &tn[p & BUKMASK], val);
    }
    __syncthreads();
    const int v0 = b << BUKSHIFT;
    int i = threadIdx.x;                     // 512 threads, one node each
    float alpha = 0.f, beta = 0.f;
    int v = v0 + i;
    if (v < N) {
        float d = dinv[v], mv = m[v];
        alpha = d * tp[i];
        beta  = d * tn[i];
        float self = d * mv;
        if (mv >= 0.f) alpha += self; else beta += self;
    }
    int lane = threadIdx.x & 63;
    for (int j = 0; j < 16; ++j) {
        float h = fmaxf(alpha * sP[j] + beta * sM[j], 0.f);
        #pragma unroll
        for (int off = 32; off > 0; off >>= 1) h += __shfl_down(h, off);
        if (lane == 0) atomicAdd(&sAcc[j], h);
    }
    __syncthreads();
    if (threadIdx.x < 16) partials[b * 16 + threadIdx.x] = sAcc[threadIdx.x];
}

// reduce partials[NBUK][16] -> mean -> out = g @ W3 + b
__global__ void k_out(const float* __restrict__ partials, const float* __restrict__ W3,
                      const float* __restrict__ b, float* __restrict__ out) {
    __shared__ float s[16][16];
    int j = threadIdx.x & 15;
    int g = threadIdx.x >> 4;
    float acc = 0.f;
    for (int blk = g; blk < NBUK; blk += 16) acc += partials[blk * 16 + j];
    s[g][j] = acc;
    __syncthreads();
    if (threadIdx.x < 16) {
        float tot = 0.f;
        #pragma unroll
        for (int gg = 0; gg < 16; ++gg) tot += s[gg][threadIdx.x];
        s[0][threadIdx.x] = tot * (1.0f / (float)N);
    }
    __syncthreads();
    if (threadIdx.x < 11) {
        float acc2 = b[threadIdx.x];
        #pragma unroll
        for (int k = 0; k < 16; ++k) acc2 += s[0][k] * W3[k * 11 + threadIdx.x];
        out[threadIdx.x] = acc2;
    }
}

extern "C" void kernel_launch(void* const* d_in, const int* in_sizes, int n_in,
                              void* d_out, int out_size, void* d_ws, size_t ws_size,
                              hipStream_t stream) {
    const float* x  = (const float*)d_in[0];
    const int*   ei = (const int*)d_in[1];   // [2*E]: rows then cols (int32)
    const float* W1 = (const float*)d_in[2];
    const float* W2 = (const float*)d_in[3];
    const float* W3 = (const float*)d_in[4];
    const float* b  = (const float*)d_in[5];
    float* out = (float*)d_out;

    int*   wsi      = (int*)d_ws;
    int*   binned   = wsi;                        // E
    float* dinv     = (float*)(wsi + E);          // N
    float* y1       = dinv + N;                   // N
    float* m        = y1 + N;                     // N
    int*   base     = (int*)(m + N);              // NBUK+1
    int*   gofs     = base + NBUK + 1;            // NBUK
    int*   gcount   = gofs + NBUK;                // NBUK
    float* partials = (float*)(gcount + NBUK);    // NBUK*16

    const int4* rows4 = (const int4*)ei;
    const int4* cols4 = (const int4*)(ei + E);

    k_init   <<<1, 256, 0, stream>>>(gcount);
    k_count  <<<256, 256, 0, stream>>>(cols4, gcount);
    k_scan   <<<1, 256, 0, stream>>>(gcount, base, gofs);
    k_scatter<<<SC_BLOCKS, 256, 0, stream>>>(rows4, cols4, gofs, binned);
    k_deg2   <<<NBUK, 256, 0, stream>>>(binned, base, x, dinv, y1);
    k_acc1   <<<NBUK, 256, 0, stream>>>(binned, base, y1, dinv, m);
    k_acc2   <<<NBUK, 512, 0, stream>>>(binned, base, m, dinv, W1, W2, partials);
    k_out    <<<1, 256, 0, stream>>>(partials, W3, b, out);
}

// Round 4
// 104.765 us; speedup vs baseline: 7.9229x; 1.2445x over previous
//
#include <hip/hip_runtime.h>

static constexpr int N = 100000;
static constexpr int E = 3200000;
static constexpr int BUKSHIFT = 8;
static constexpr int BUKSZ = 1 << BUKSHIFT;             // 256 nodes / bucket
static constexpr int BUKMASK = BUKSZ - 1;
static constexpr int NBUK = (N + BUKSZ - 1) / BUKSZ;    // 391
static constexpr int CAP = 12288;                        // slots per bucket region
static constexpr int SC_CHUNK = 8192;
static constexpr int SC_T = 1024;
static constexpr int SC_BLOCKS = (E + SC_CHUNK - 1) / SC_CHUNK;  // 391

// ws (4B elems): binned[NBUK*CAP] | dinv[N] | y1[N] | m[N] | gofs[NBUK] | partials[NBUK*16]

__global__ void k_init(int* __restrict__ gofs) {
    int i = threadIdx.x;
    if (i < NBUK) gofs[i] = i * CAP;
}

// Block-local counting sort of 8192 edges by destination bucket, then
// bucket-contiguous (coalesced-run) writes into fixed-capacity regions.
__global__ __launch_bounds__(SC_T) void k_scatter(const int4* __restrict__ rows4,
                                                  const int4* __restrict__ cols4,
                                                  int* __restrict__ gofs,
                                                  int* __restrict__ binned) {
    __shared__ int hist[4][NBUK];   // replica hists -> replica-exclusive bases
    __shared__ int cnt[512];        // padded, scanned inclusive
    __shared__ int lbase[NBUK];
    __shared__ int gbase[NBUK];
    __shared__ int stag[SC_CHUNK];

    const int tid = threadIdx.x;
    const int g = tid >> 8;         // 4 replica groups
    for (int i = tid; i < 4 * NBUK; i += SC_T) (&hist[0][0])[i] = 0;
    if (tid < 512) cnt[tid] = 0;
    __syncthreads();

    const int nI4 = E / 4;
    const int base4 = blockIdx.x * (SC_CHUNK / 4);
    const int ia = base4 + tid, ib = base4 + 1024 + tid;
    const bool va = ia < nI4, vb = ib < nI4;
    int4 ra, ca, rb, cb;
    if (va) { ra = rows4[ia]; ca = cols4[ia]; }
    if (vb) { rb = rows4[ib]; cb = cols4[ib]; }

    if (va) {
        atomicAdd(&hist[g][ca.x >> BUKSHIFT], 1);
        atomicAdd(&hist[g][ca.y >> BUKSHIFT], 1);
        atomicAdd(&hist[g][ca.z >> BUKSHIFT], 1);
        atomicAdd(&hist[g][ca.w >> BUKSHIFT], 1);
    }
    if (vb) {
        atomicAdd(&hist[g][cb.x >> BUKSHIFT], 1);
        atomicAdd(&hist[g][cb.y >> BUKSHIFT], 1);
        atomicAdd(&hist[g][cb.z >> BUKSHIFT], 1);
        atomicAdd(&hist[g][cb.w >> BUKSHIFT], 1);
    }
    __syncthreads();

    if (tid < NBUK) {
        int h0 = hist[0][tid], h1 = hist[1][tid], h2 = hist[2][tid], h3 = hist[3][tid];
        hist[0][tid] = 0; hist[1][tid] = h0; hist[2][tid] = h0 + h1; hist[3][tid] = h0 + h1 + h2;
        int c = h0 + h1 + h2 + h3;
        cnt[tid] = c;
        gbase[tid] = c ? atomicAdd(&gofs[tid], c) : 0;
    }
    __syncthreads();
    for (int off = 1; off < 512; off <<= 1) {
        int v = 0;
        if (tid < 512) { v = cnt[tid]; if (tid >= off) v += cnt[tid - off]; }
        __syncthreads();
        if (tid < 512) cnt[tid] = v;
        __syncthreads();
    }
    if (tid < NBUK) lbase[tid] = tid ? cnt[tid - 1] : 0;
    __syncthreads();

    if (va) {
        int b, off;
        b = ca.x >> BUKSHIFT; off = atomicAdd(&hist[g][b], 1); stag[lbase[b] + off] = (ra.x << BUKSHIFT) | (ca.x & BUKMASK);
        b = ca.y >> BUKSHIFT; off = atomicAdd(&hist[g][b], 1); stag[lbase[b] + off] = (ra.y << BUKSHIFT) | (ca.y & BUKMASK);
        b = ca.z >> BUKSHIFT; off = atomicAdd(&hist[g][b], 1); stag[lbase[b] + off] = (ra.z << BUKSHIFT) | (ca.z & BUKMASK);
        b = ca.w >> BUKSHIFT; off = atomicAdd(&hist[g][b], 1); stag[lbase[b] + off] = (ra.w << BUKSHIFT) | (ca.w & BUKMASK);
    }
    if (vb) {
        int b, off;
        b = cb.x >> BUKSHIFT; off = atomicAdd(&hist[g][b], 1); stag[lbase[b] + off] = (rb.x << BUKSHIFT) | (cb.x & BUKMASK);
        b = cb.y >> BUKSHIFT; off = atomicAdd(&hist[g][b], 1); stag[lbase[b] + off] = (rb.y << BUKSHIFT) | (cb.y & BUKMASK);
        b = cb.z >> BUKSHIFT; off = atomicAdd(&hist[g][b], 1); stag[lbase[b] + off] = (rb.z << BUKSHIFT) | (cb.z & BUKMASK);
        b = cb.w >> BUKSHIFT; off = atomicAdd(&hist[g][b], 1); stag[lbase[b] + off] = (rb.w << BUKSHIFT) | (cb.w & BUKMASK);
    }
    __syncthreads();

    const int eTot = min(SC_CHUNK, E - blockIdx.x * SC_CHUNK);
    int s = tid * 8;
    if (s < eTot) {
        int lo = 0, hi = NBUK - 1;
        while (lo < hi) { int mid = (lo + hi + 1) >> 1; if (lbase[mid] <= s) lo = mid; else hi = mid - 1; }
        int b = lo;
        const int e1 = min(s + 8, eTot);
        for (; s < e1; ++s) {
            while (b + 1 < NBUK && lbase[b + 1] <= s) ++b;
            binned[gbase[b] + (s - lbase[b])] = stag[s];
        }
    }
}

// per-bucket degree -> dinv, y1
__global__ void k_deg(const int* __restrict__ binned, const int* __restrict__ gofs,
                      const float* __restrict__ x, float* __restrict__ dinv,
                      float* __restrict__ y1) {
    __shared__ int cnt[2][BUKSZ];
    const int tid = threadIdx.x;
    cnt[0][tid] = 0; cnt[1][tid] = 0;
    __syncthreads();
    const int b = blockIdx.x, g = tid >> 7;
    const int s1 = gofs[b];
    for (int i = b * CAP + tid; i < s1; i += 256)
        atomicAdd(&cnt[g][binned[i] & BUKMASK], 1);
    __syncthreads();
    const int v = (b << BUKSHIFT) + tid;
    if (v < N) {
        float d = rsqrtf(1.0f + (float)(cnt[0][tid] + cnt[1][tid]));
        dinv[v] = d;
        y1[v] = d * x[v];
    }
}

// per-bucket acc1 -> m
__global__ void k_acc1(const int* __restrict__ binned, const int* __restrict__ gofs,
                       const float* __restrict__ y1, const float* __restrict__ dinv,
                       float* __restrict__ m) {
    __shared__ float acc[2][BUKSZ];
    const int tid = threadIdx.x;
    acc[0][tid] = 0.f; acc[1][tid] = 0.f;
    __syncthreads();
    const int b = blockIdx.x, g = tid >> 7;
    const int s1 = gofs[b];
    for (int i = b * CAP + tid; i < s1; i += 256) {
        int p = binned[i];
        atomicAdd(&acc[g][p & BUKMASK], y1[p >> BUKSHIFT]);
    }
    __syncthreads();
    const int v = (b << BUKSHIFT) + tid;
    if (v < N) {
        float d = dinv[v];
        float s = d * (acc[0][tid] + acc[1][tid]) + d * y1[v];
        m[v] = d * s;
    }
}

// per-bucket tpos/tneg -> h2 -> per-block partial column sums
__global__ void k_acc2(const int* __restrict__ binned, const int* __restrict__ gofs,
                       const float* __restrict__ m, const float* __restrict__ dinv,
                       const float* __restrict__ W1, const float* __restrict__ W2,
                       float* __restrict__ partials) {
    __shared__ float tp[2][BUKSZ], tn[2][BUKSZ];
    __shared__ float sP[16], sM[16], sAcc[16];
    const int tid = threadIdx.x;
    if (tid < 16) {
        float p = 0.f, q = 0.f;
        for (int k = 0; k < 16; ++k) {
            float w1 = W1[k];
            float w2 = W2[k * 16 + tid];
            p += fmaxf(w1, 0.f) * w2;
            q += fminf(w1, 0.f) * w2;
        }
        sP[tid] = p; sM[tid] = q; sAcc[tid] = 0.f;
    }
    tp[0][tid] = 0.f; tp[1][tid] = 0.f; tn[0][tid] = 0.f; tn[1][tid] = 0.f;
    __syncthreads();
    const int b = blockIdx.x, g = tid >> 7;
    const int s1 = gofs[b];
    for (int i = b * CAP + tid; i < s1; i += 256) {
        int p = binned[i];
        float val = m[p >> BUKSHIFT];
        atomicAdd(val >= 0.f ? &tp[g][p & BUKMASK] : &tn[g][p & BUKMASK], val);
    }
    __syncthreads();
    const int v = (b << BUKSHIFT) + tid;
    float alpha = 0.f, beta = 0.f;
    if (v < N) {
        float d = dinv[v], mv = m[v];
        alpha = d * (tp[0][tid] + tp[1][tid]);
        beta  = d * (tn[0][tid] + tn[1][tid]);
        float self = d * mv;
        if (mv >= 0.f) alpha += self; else beta += self;
    }
    const int lane = tid & 63;
    for (int j = 0; j < 16; ++j) {
        float h = fmaxf(alpha * sP[j] + beta * sM[j], 0.f);
        #pragma unroll
        for (int off = 32; off > 0; off >>= 1) h += __shfl_down(h, off);
        if (lane == 0) atomicAdd(&sAcc[j], h);
    }
    __syncthreads();
    if (tid < 16) partials[b * 16 + tid] = sAcc[tid];
}

// reduce partials[NBUK][16] -> mean -> out = g @ W3 + b
__global__ void k_out(const float* __restrict__ partials, const float* __restrict__ W3,
                      const float* __restrict__ b, float* __restrict__ out) {
    __shared__ float s[16][16];
    int j = threadIdx.x & 15;
    int g = threadIdx.x >> 4;
    float acc = 0.f;
    for (int blk = g; blk < NBUK; blk += 16) acc += partials[blk * 16 + j];
    s[g][j] = acc;
    __syncthreads();
    if (threadIdx.x < 16) {
        float tot = 0.f;
        #pragma unroll
        for (int gg = 0; gg < 16; ++gg) tot += s[gg][threadIdx.x];
        s[0][threadIdx.x] = tot * (1.0f / (float)N);
    }
    __syncthreads();
    if (threadIdx.x < 11) {
        float acc2 = b[threadIdx.x];
        #pragma unroll
        for (int k = 0; k < 16; ++k) acc2 += s[0][k] * W3[k * 11 + threadIdx.x];
        out[threadIdx.x] = acc2;
    }
}

extern "C" void kernel_launch(void* const* d_in, const int* in_sizes, int n_in,
                              void* d_out, int out_size, void* d_ws, size_t ws_size,
                              hipStream_t stream) {
    const float* x  = (const float*)d_in[0];
    const int*   ei = (const int*)d_in[1];   // [2*E]: rows then cols (int32)
    const float* W1 = (const float*)d_in[2];
    const float* W2 = (const float*)d_in[3];
    const float* W3 = (const float*)d_in[4];
    const float* b  = (const float*)d_in[5];
    float* out = (float*)d_out;

    int*   wsi      = (int*)d_ws;
    int*   binned   = wsi;                             // NBUK*CAP
    float* dinv     = (float*)(wsi + (size_t)NBUK * CAP);
    float* y1       = dinv + N;
    float* m        = y1 + N;
    int*   gofs     = (int*)(m + N);                   // NBUK
    float* partials = (float*)(gofs + NBUK);           // NBUK*16

    const int4* rows4 = (const int4*)ei;
    const int4* cols4 = (const int4*)(ei + E);

    k_init   <<<1, 512, 0, stream>>>(gofs);
    k_scatter<<<SC_BLOCKS, SC_T, 0, stream>>>(rows4, cols4, gofs, binned);
    k_deg    <<<NBUK, 256, 0, stream>>>(binned, gofs, x, dinv, y1);
    k_acc1   <<<NBUK, 256, 0, stream>>>(binned, gofs, y1, dinv, m);
    k_acc2   <<<NBUK, 256, 0, stream>>>(binned, gofs, m, dinv, W1, W2, partials);
    k_out    <<<1, 256, 0, stream>>>(partials, W3, b, out);
}